// Round 18
// baseline (297.641 us; speedup 1.0000x reference)
//
#include <hip/hip_runtime.h>
#include <stdint.h>

#define ROWS 8192        // B*N
#define CAP 64           // per-(dir,expert) list cap: mean 20.5, sd 4.5 -> +9.6 sigma
#define NSTEPS 5
#define ZROW 8192        // sentinel: zeroed row appended to hbf (fits u16)

typedef short bf16x8 __attribute__((ext_vector_type(8)));
typedef float f32x4 __attribute__((ext_vector_type(4)));
typedef float f32x2 __attribute__((ext_vector_type(2)));
typedef unsigned short u16;
typedef unsigned int u32;

__device__ __forceinline__ float bf2f(u16 u){ union{u32 i; float f;} x; x.i=(u32)u<<16; return x.f; }
__device__ __forceinline__ u16 f2bf(float f){ union{float f; u32 i;} x; x.f=f; u32 r = x.i + 0x7fffu + ((x.i>>16)&1u); return (u16)(r>>16); }

#define MFMA __builtin_amdgcn_mfma_f32_16x16x32_bf16
// LDS swizzle (G4): XOR row bits into 16B-slot bits to break power-of-2 stride aliasing
#define SWZ(r, byte) ((byte) ^ (((r)&7)<<4))
#define ZPAD 130         // z/hh row stride in u16 (conflict-free)

// ---------------- prep ----------------

__device__ __forceinline__ float wsel(const float* __restrict__ Wr, const float* __restrict__ Wz,
                                      const float* __restrict__ Wh, int f, int o){
  if (o < 128) return Wr[(size_t)f*128 + o];
  if (o < 256) return Wz[(size_t)f*128 + (o-128)];
  return (f < 256) ? Wh[(size_t)f*128 + (o-256)] : 0.f;
}

// blocks [0,4096): init hf/hbf. blocks >=4096: fold weights. block 4096 zeroes the sentinel row.
__global__ void k_prep(const float* __restrict__ prop, float* __restrict__ hf, u16* __restrict__ hbf,
                       const float* __restrict__ W_in, const float* __restrict__ b_in,
                       const float* __restrict__ W_out, const float* __restrict__ b_out,
                       const float* __restrict__ W_r, const float* __restrict__ W_z,
                       const float* __restrict__ W_h,
                       u16* __restrict__ WfT, float* __restrict__ bv, u16* __restrict__ WhbT)
{
  int bid = blockIdx.x;
  if (bid < 4096){
    int i = bid*256 + threadIdx.x;
    float v = prop[i]; hf[i] = v; hbf[i] = f2bf(v);
    return;
  }
  if (bid == 4096 && threadIdx.x < 128) hbf[(size_t)ZROW*128 + threadIdx.x] = 0;  // sentinel row
  int i = (bid-4096)*256 + threadIdx.x;
  if (i < 640*384){                       // WfT[o][k], lanes over o (coalesced)
    int k = i/384, o = i - k*384;
    float s;
    if (k >= 512){
      s = wsel(W_r, W_z, W_h, 256 + (k-512), o);
    } else {
      const float* Wrow; int fb;
      if (k < 256){ Wrow = W_in  + (size_t)((k>>7)&1)*16384 + (size_t)(k&127)*128; fb = 0; }
      else { int kk = k-256; Wrow = W_out + (size_t)(kk>>7)*16384 + (size_t)(kk&127)*128; fb = 128; }
      s = 0.f;
#pragma unroll 8
      for (int f=0; f<128; f++) s += Wrow[f] * wsel(W_r, W_z, W_h, fb+f, o);
    }
    WfT[(size_t)o*640 + k] = f2bf(s);
  } else if (i < 640*384 + 4*384){
    int j = i - 640*384; int q = j / 384, o = j - q*384;
    const float* bp = (q < 2) ? (b_in + q*128) : (b_out + (q-2)*128);
    int fb = (q < 2) ? 0 : 128;
    float s = 0.f;
#pragma unroll 8
    for (int f=0; f<128; f++) s += bp[f] * wsel(W_r, W_z, W_h, fb+f, o);
    bv[j] = s;
  } else if (i < 640*384 + 4*384 + 128*128){
    int j = i - (640*384 + 4*384); int kk = j>>7, o = j&127;
    WhbT[(size_t)o*128 + kk] = f2bf(W_h[(size_t)(256+kk)*128 + o]);
  }
}

// CSR via block-local LDS lists; stores ABSOLUTE node index (batch*2048 + n) as u16.
__global__ void k_csr(const float* __restrict__ A,
                      u16* __restrict__ idx4, int* __restrict__ cnt4)
{
  __shared__ int scnt[4];
  __shared__ int slist[4][CAP];
  int row = blockIdx.x, tid = threadIdx.x;
  if (tid < 4) scnt[tid] = 0;
  __syncthreads();
  const float* ar = A + (size_t)row * 8192;
  int babs = (row>>11)<<11;
  for (int c = tid*4; c < 8192; c += 1024){
    f32x4 v = __builtin_nontemporal_load(reinterpret_cast<const f32x4*>(ar + c));
    float vv[4] = {v.x, v.y, v.z, v.w};
#pragma unroll
    for (int j=0;j<4;j++){
      if (vv[j] != 0.f){
        int m = c + j;
        int lst = ((m>>12)<<1) | (m&1);
        int n = (m & 4095) >> 1;
        int p = atomicAdd(&scnt[lst], 1);
        if (p < CAP) slist[lst][p] = babs | n;
      }
    }
  }
  __syncthreads();
  if (tid < 4) cnt4[(row<<2) + tid] = scnt[tid];
  for (int j = tid; j < 4*CAP; j += 256){
    int l = j>>6, p = j&63;
    int c = scnt[l]; if (c > CAP) c = CAP;
    if (p < c) __builtin_nontemporal_store((u16)slist[l][p],
                  idx4 + (((size_t)(row<<2) + l)<<6) + p);
  }
}

// ---------------- fused per-step kernel: 32 rows/block, 256 blocks, XCD batch-affinity ----------------
// gather: 16 lists/wave single pass, readlane->SGPR-base, depth-2 pipeline, f32x2 accum.
// R18 polish: no entry barrier -- gather reads cnt4 via scalar loads (wave-uniform index);
// cnts LDS copy (epilogue-only) is covered by the gather-end barrier.
__global__ __launch_bounds__(512, 2) void k_fused(
    const int* __restrict__ cnt4, const u16* __restrict__ idx4,
    const u16* __restrict__ WfT, const float* __restrict__ bv,
    const float* __restrict__ b_r, const float* __restrict__ b_z, const float* __restrict__ b_h,
    const u16* __restrict__ WhbT, float* __restrict__ hf, u16* __restrict__ hbf)
{
  __shared__ u16  X_s[32*512];       // gathered sums, swizzled rows (stride 1024B)
  __shared__ u16  rh_s[32*128];      // r*h, swizzled rows (stride 256B)
  __shared__ u16  z_s[32*ZPAD];      // z as u16 fixed-point, padded stride
  __shared__ u16  hh_s[32*ZPAD];     // pre-tanh partial, bf16, padded stride
  __shared__ int  cnts[32][4];

  int tid  = threadIdx.x;
  int wave = tid>>6, lane = tid&63, lr = lane&15, lk = lane>>4;

  // batch-affinity remap: dispatch d -> XCD d%8. batch q = xcd>>1 gets XCD pair.
  int d = blockIdx.x;
  int xcd = d & 7, slot = d >> 3;
  int r_blk = ((xcd>>1)<<6) | ((slot<<1) | (xcd&1));
  int m0 = r_blk*32;

  // cnts copy for epilogue 1 only; visibility guaranteed by the gather-end __syncthreads()
  if (tid < 128) cnts[tid>>2][tid&3] = cnt4[((m0 + (tid>>2))<<2) + (tid&3)];

  // ---- gather: 16 lists per wave, one pass, scalar-base loads; counts via s_load ----
  {
    int base_l = wave*16;
    int cc[16], my[16];
#pragma unroll
    for (int j=0;j<16;j++){
      int l = base_l + j;
      int lid = ((m0 + (l>>2))<<2) | (l&3);          // wave-uniform -> scalar load
      int c = cnt4[lid]; if (c > CAP) c = CAP;
      cc[j] = c;
      my[j] = (lane < c) ? (int)idx4[(((size_t)lid)<<6) + lane] : ZROW;
    }
    int cmax = 0;
#pragma unroll
    for (int j=0;j<16;j++) cmax = max(cmax, cc[j]);

    const u16* hb = hbf + (lane<<1);
    f32x2 a[16];
#pragma unroll
    for (int j=0;j<16;j++) a[j] = (f32x2){0.f, 0.f};

    u32 v[16];
#pragma unroll
    for (int j=0;j<16;j++){
      int n = __builtin_amdgcn_readlane(my[j], 0);   // uniform -> SGPR base
      v[j] = *reinterpret_cast<const u32*>(hb + ((size_t)n<<7));
    }
    for (int i=1; i<cmax; i++){
      u32 vn[16];
#pragma unroll
      for (int j=0;j<16;j++){
        int n = __builtin_amdgcn_readlane(my[j], i);
        vn[j] = *reinterpret_cast<const u32*>(hb + ((size_t)n<<7));
      }
#pragma unroll
      for (int j=0;j<16;j++){
        union{u32 u; float f;} lo, hi;
        lo.u = v[j]<<16; hi.u = v[j] & 0xffff0000u;
        a[j] += (f32x2){lo.f, hi.f};                 // v_pk_add_f32
        v[j] = vn[j];
      }
    }
    if (cmax > 0){
#pragma unroll
      for (int j=0;j<16;j++){
        union{u32 u; float f;} lo, hi;
        lo.u = v[j]<<16; hi.u = v[j] & 0xffff0000u;
        a[j] += (f32x2){lo.f, hi.f};
      }
    }
#pragma unroll
    for (int j=0;j<16;j++){
      int l = base_l + j, rl = l>>2, q = l&3;
      u32 pk = ((u32)f2bf(a[j].y)<<16) | (u32)f2bf(a[j].x);
      *reinterpret_cast<u32*>((char*)X_s + SWZ(rl, rl*1024 + q*256 + lane*4)) = pk;
    }
  }
  __syncthreads();

  // ---- GEMM1: pre[32x384] = [X_s | hbf] @ WfT^T ; wave tile 32(m) x 48(n) ----
  int n0 = wave*48;
  f32x4 acc[2][3] = {};
  const u16* Ah = hbf + (size_t)(m0+lr)*128 + lk*8;
  const u16* Bw = WfT + (size_t)(n0+lr)*640 + lk*8;
#pragma unroll
  for (int k=0;k<512;k+=32){
    bf16x8 b0 = *reinterpret_cast<const bf16x8*>(Bw + k);
    bf16x8 b1 = *reinterpret_cast<const bf16x8*>(Bw + 16*640 + k);
    bf16x8 b2 = *reinterpret_cast<const bf16x8*>(Bw + 32*640 + k);
#pragma unroll
    for (int mt=0;mt<2;mt++){
      int row = mt*16 + lr;
      bf16x8 aa = *reinterpret_cast<const bf16x8*>((const char*)X_s + SWZ(row, row*1024 + (k + lk*8)*2));
      acc[mt][0] = MFMA(aa, b0, acc[mt][0], 0,0,0);
      acc[mt][1] = MFMA(aa, b1, acc[mt][1], 0,0,0);
      acc[mt][2] = MFMA(aa, b2, acc[mt][2], 0,0,0);
    }
  }
#pragma unroll
  for (int k=0;k<128;k+=32){
    bf16x8 b0 = *reinterpret_cast<const bf16x8*>(Bw + 512 + k);
    bf16x8 b1 = *reinterpret_cast<const bf16x8*>(Bw + 16*640 + 512 + k);
    bf16x8 b2 = *reinterpret_cast<const bf16x8*>(Bw + 32*640 + 512 + k);
#pragma unroll
    for (int mt=0;mt<2;mt++){
      bf16x8 aa = *reinterpret_cast<const bf16x8*>(Ah + (size_t)mt*16*128 + k);
      acc[mt][0] = MFMA(aa, b0, acc[mt][0], 0,0,0);
      acc[mt][1] = MFMA(aa, b1, acc[mt][1], 0,0,0);
      acc[mt][2] = MFMA(aa, b2, acc[mt][2], 0,0,0);
    }
  }

  // ---- epilogue 1: r -> rh_s (swizzled), z -> z_s, hh -> hh_s ----
#pragma unroll
  for (int nt=0;nt<3;nt++){
    int oo = n0 + nt*16 + lr;
    float base = (oo<128) ? b_r[oo] : (oo<256) ? b_z[oo-128] : b_h[oo-256];
    float q0 = bv[oo], q1 = bv[384+oo], q2 = bv[768+oo], q3 = bv[1152+oo];
#pragma unroll
    for (int mt=0;mt<2;mt++){
#pragma unroll
      for (int i2=0;i2<4;i2++){
        int rl = mt*16 + lk*4 + i2;
        float v = acc[mt][nt][i2] + base
                + cnts[rl][0]*q0 + cnts[rl][1]*q1 + cnts[rl][2]*q2 + cnts[rl][3]*q3;
        if (oo < 128){
          float s = 1.f/(1.f + expf(-v));
          float hv = hf[(size_t)(m0+rl)*128 + oo];
          *reinterpret_cast<u16*>((char*)rh_s + SWZ(rl, rl*256 + oo*2)) = f2bf(s*hv);
        } else if (oo < 256){
          float s = 1.f/(1.f + expf(-v));
          z_s[rl*ZPAD + (oo-128)] = (u16)(s*65535.f + 0.5f);
        } else {
          hh_s[rl*ZPAD + (oo-256)] = f2bf(v);
        }
      }
    }
  }
  __syncthreads();

  // ---- GEMM2: H2[32x128] = rh_s @ WhbT^T ; wave tile 32(m) x 16(n) ----
  int c0 = wave*16;
  f32x4 acc2[2] = {};
  const u16* Bh = WhbT + (size_t)(c0+lr)*128 + lk*8;
#pragma unroll
  for (int k=0;k<128;k+=32){
    bf16x8 b = *reinterpret_cast<const bf16x8*>(Bh + k);
#pragma unroll
    for (int mt=0;mt<2;mt++){
      int rr = mt*16 + lr;
      bf16x8 aa = *reinterpret_cast<const bf16x8*>((char*)rh_s + SWZ(rr, rr*256 + (k + lk*8)*2));
      acc2[mt] = MFMA(aa, b, acc2[mt], 0,0,0);
    }
  }

  // ---- epilogue 2: h update ----
#pragma unroll
  for (int mt=0;mt<2;mt++){
#pragma unroll
    for (int i2=0;i2<4;i2++){
      int rl = mt*16 + lk*4 + i2, col = c0 + lr;
      size_t ix = (size_t)(m0+rl)*128 + col;
      float hhat = tanhf(acc2[mt][i2] + bf2f(hh_s[rl*ZPAD + col]));
      float zz = (float)z_s[rl*ZPAD + col] * (1.f/65535.f);
      float ho = hf[ix];
      float hn = ho + zz*(hhat - ho);
      hf[ix] = hn;
      hbf[ix] = f2bf(hn);
    }
  }
}

// ---------------- host ----------------

extern "C" void kernel_launch(void* const* d_in, const int* in_sizes, int n_in,
                              void* d_out, int out_size, void* d_ws, size_t ws_size,
                              hipStream_t stream)
{
  const float* prop  = (const float*)d_in[0];
  const float* A     = (const float*)d_in[1];
  const float* W_in  = (const float*)d_in[2];
  const float* b_in  = (const float*)d_in[3];
  const float* W_out = (const float*)d_in[4];
  const float* b_out = (const float*)d_in[5];
  const float* W_r   = (const float*)d_in[6];
  const float* b_r   = (const float*)d_in[7];
  const float* W_z   = (const float*)d_in[8];
  const float* b_z   = (const float*)d_in[9];
  const float* W_h   = (const float*)d_in[10];
  const float* b_h   = (const float*)d_in[11];

  char* ws = (char*)d_ws;
  size_t off = 0;
  auto nxt = [&](size_t bytes)->char*{ char* p = ws + off; off += (bytes + 255) & ~(size_t)255; return p; };
  int*   cnt4  = (int*)  nxt((size_t)ROWS*4*4);
  u16*   idx4  = (u16*)  nxt((size_t)ROWS*4*CAP*2);
  u16*   hbf   = (u16*)  nxt((size_t)(ROWS+1)*128*2);   // +1 sentinel zero row
  float* hf    = (float*)nxt((size_t)ROWS*128*4);
  u16*   WfT   = (u16*)  nxt((size_t)384*640*2);
  float* bv    = (float*)nxt((size_t)4*384*4);
  u16*   WhbT  = (u16*)  nxt((size_t)128*128*2);

  int fold_blocks = (640*384 + 4*384 + 128*128 + 255)/256;
  k_prep<<<4096 + fold_blocks, 256, 0, stream>>>(prop, hf, hbf,
      W_in, b_in, W_out, b_out, W_r, W_z, W_h, WfT, bv, WhbT);
  k_csr<<<ROWS, 256, 0, stream>>>(A, idx4, cnt4);

  for (int t=0; t<NSTEPS; t++){
    k_fused<<<ROWS/32, 512, 0, stream>>>(cnt4, idx4, WfT, bv, b_r, b_z, b_h, WhbT, hf, hbf);
  }

  hipMemcpyAsync(d_out, hf, (size_t)ROWS*128*4, hipMemcpyDeviceToDevice, stream);
}

// Round 19
// 290.333 us; speedup vs baseline: 1.0252x; 1.0252x over previous
//
#include <hip/hip_runtime.h>
#include <stdint.h>

#define ROWS 8192        // B*N
#define CAP 64           // per-(dir,expert) list cap: mean 20.5, sd 4.5 -> +9.6 sigma
#define NSTEPS 5
#define ZROW 8192        // sentinel: zeroed row appended to hbf (fits u16)

typedef short bf16x8 __attribute__((ext_vector_type(8)));
typedef float f32x4 __attribute__((ext_vector_type(4)));
typedef float f32x2 __attribute__((ext_vector_type(2)));
typedef unsigned short u16;
typedef unsigned int u32;

__device__ __forceinline__ float bf2f(u16 u){ union{u32 i; float f;} x; x.i=(u32)u<<16; return x.f; }
__device__ __forceinline__ u16 f2bf(float f){ union{float f; u32 i;} x; x.f=f; u32 r = x.i + 0x7fffu + ((x.i>>16)&1u); return (u16)(r>>16); }

#define MFMA __builtin_amdgcn_mfma_f32_16x16x32_bf16
// LDS swizzle (G4): XOR row bits into 16B-slot bits to break power-of-2 stride aliasing
#define SWZ(r, byte) ((byte) ^ (((r)&7)<<4))
#define ZPAD 130         // z/hh row stride in u16 (conflict-free)

// ---------------- prep ----------------

__device__ __forceinline__ float wsel(const float* __restrict__ Wr, const float* __restrict__ Wz,
                                      const float* __restrict__ Wh, int f, int o){
  if (o < 128) return Wr[(size_t)f*128 + o];
  if (o < 256) return Wz[(size_t)f*128 + (o-128)];
  return (f < 256) ? Wh[(size_t)f*128 + (o-256)] : 0.f;
}

// blocks [0,4096): init hf/hbf. blocks >=4096: fold weights. block 4096 zeroes the sentinel row.
__global__ void k_prep(const float* __restrict__ prop, float* __restrict__ hf, u16* __restrict__ hbf,
                       const float* __restrict__ W_in, const float* __restrict__ b_in,
                       const float* __restrict__ W_out, const float* __restrict__ b_out,
                       const float* __restrict__ W_r, const float* __restrict__ W_z,
                       const float* __restrict__ W_h,
                       u16* __restrict__ WfT, float* __restrict__ bv, u16* __restrict__ WhbT)
{
  int bid = blockIdx.x;
  if (bid < 4096){
    int i = bid*256 + threadIdx.x;
    float v = prop[i]; hf[i] = v; hbf[i] = f2bf(v);
    return;
  }
  if (bid == 4096 && threadIdx.x < 128) hbf[(size_t)ZROW*128 + threadIdx.x] = 0;  // sentinel row
  int i = (bid-4096)*256 + threadIdx.x;
  if (i < 640*384){                       // WfT[o][k], lanes over o (coalesced)
    int k = i/384, o = i - k*384;
    float s;
    if (k >= 512){
      s = wsel(W_r, W_z, W_h, 256 + (k-512), o);
    } else {
      const float* Wrow; int fb;
      if (k < 256){ Wrow = W_in  + (size_t)((k>>7)&1)*16384 + (size_t)(k&127)*128; fb = 0; }
      else { int kk = k-256; Wrow = W_out + (size_t)(kk>>7)*16384 + (size_t)(kk&127)*128; fb = 128; }
      s = 0.f;
#pragma unroll 8
      for (int f=0; f<128; f++) s += Wrow[f] * wsel(W_r, W_z, W_h, fb+f, o);
    }
    WfT[(size_t)o*640 + k] = f2bf(s);
  } else if (i < 640*384 + 4*384){
    int j = i - 640*384; int q = j / 384, o = j - q*384;
    const float* bp = (q < 2) ? (b_in + q*128) : (b_out + (q-2)*128);
    int fb = (q < 2) ? 0 : 128;
    float s = 0.f;
#pragma unroll 8
    for (int f=0; f<128; f++) s += bp[f] * wsel(W_r, W_z, W_h, fb+f, o);
    bv[j] = s;
  } else if (i < 640*384 + 4*384 + 128*128){
    int j = i - (640*384 + 4*384); int kk = j>>7, o = j&127;
    WhbT[(size_t)o*128 + kk] = f2bf(W_h[(size_t)(256+kk)*128 + o]);
  }
}

// CSR via block-local LDS lists; stores ABSOLUTE node index (batch*2048 + n) as u16.
__global__ void k_csr(const float* __restrict__ A,
                      u16* __restrict__ idx4, int* __restrict__ cnt4)
{
  __shared__ int scnt[4];
  __shared__ int slist[4][CAP];
  int row = blockIdx.x, tid = threadIdx.x;
  if (tid < 4) scnt[tid] = 0;
  __syncthreads();
  const float* ar = A + (size_t)row * 8192;
  int babs = (row>>11)<<11;
  for (int c = tid*4; c < 8192; c += 1024){
    f32x4 v = __builtin_nontemporal_load(reinterpret_cast<const f32x4*>(ar + c));
    float vv[4] = {v.x, v.y, v.z, v.w};
#pragma unroll
    for (int j=0;j<4;j++){
      if (vv[j] != 0.f){
        int m = c + j;
        int lst = ((m>>12)<<1) | (m&1);
        int n = (m & 4095) >> 1;
        int p = atomicAdd(&scnt[lst], 1);
        if (p < CAP) slist[lst][p] = babs | n;
      }
    }
  }
  __syncthreads();
  if (tid < 4) cnt4[(row<<2) + tid] = scnt[tid];
  for (int j = tid; j < 4*CAP; j += 256){
    int l = j>>6, p = j&63;
    int c = scnt[l]; if (c > CAP) c = CAP;
    if (p < c) __builtin_nontemporal_store((u16)slist[l][p],
                  idx4 + (((size_t)(row<<2) + l)<<6) + p);
  }
}

// ---------------- fused per-step kernel: 32 rows/block, 256 blocks, XCD batch-affinity ----------------
// gather: 16 lists/wave single pass, readlane->SGPR-base, depth-2 pipeline, f32x2 accum.
__global__ __launch_bounds__(512, 2) void k_fused(
    const int* __restrict__ cnt4, const u16* __restrict__ idx4,
    const u16* __restrict__ WfT, const float* __restrict__ bv,
    const float* __restrict__ b_r, const float* __restrict__ b_z, const float* __restrict__ b_h,
    const u16* __restrict__ WhbT, float* __restrict__ hf, u16* __restrict__ hbf)
{
  __shared__ u16  X_s[32*512];       // gathered sums, swizzled rows (stride 1024B)
  __shared__ u16  rh_s[32*128];      // r*h, swizzled rows (stride 256B)
  __shared__ u16  z_s[32*ZPAD];      // z as u16 fixed-point, padded stride
  __shared__ u16  hh_s[32*ZPAD];     // pre-tanh partial, bf16, padded stride
  __shared__ int  cnts[32][4];

  int tid  = threadIdx.x;
  int wave = tid>>6, lane = tid&63, lr = lane&15, lk = lane>>4;

  // batch-affinity remap: dispatch d -> XCD d%8. batch q = xcd>>1 gets XCD pair.
  int d = blockIdx.x;
  int xcd = d & 7, slot = d >> 3;
  int r_blk = ((xcd>>1)<<6) | ((slot<<1) | (xcd&1));
  int m0 = r_blk*32;

  if (tid < 128) cnts[tid>>2][tid&3] = cnt4[((m0 + (tid>>2))<<2) + (tid&3)];
  __syncthreads();

  // ---- gather: 16 lists per wave, one pass, scalar-base loads ----
  {
    int base_l = wave*16;
    int cc[16], my[16];
#pragma unroll
    for (int j=0;j<16;j++){
      int l = base_l + j;
      int c = cnts[l>>2][l&3]; if (c > CAP) c = CAP;
      cc[j] = c;
      int lid = ((m0 + (l>>2))<<2) | (l&3);
      my[j] = (lane < c) ? (int)idx4[(((size_t)lid)<<6) + lane] : ZROW;
    }
    int cmax = 0;
#pragma unroll
    for (int j=0;j<16;j++) cmax = max(cmax, cc[j]);

    const u16* hb = hbf + (lane<<1);
    f32x2 a[16];
#pragma unroll
    for (int j=0;j<16;j++) a[j] = (f32x2){0.f, 0.f};

    u32 v[16];
#pragma unroll
    for (int j=0;j<16;j++){
      int n = __builtin_amdgcn_readlane(my[j], 0);   // uniform -> SGPR base
      v[j] = *reinterpret_cast<const u32*>(hb + ((size_t)n<<7));
    }
    for (int i=1; i<cmax; i++){
      u32 vn[16];
#pragma unroll
      for (int j=0;j<16;j++){
        int n = __builtin_amdgcn_readlane(my[j], i);
        vn[j] = *reinterpret_cast<const u32*>(hb + ((size_t)n<<7));
      }
#pragma unroll
      for (int j=0;j<16;j++){
        union{u32 u; float f;} lo, hi;
        lo.u = v[j]<<16; hi.u = v[j] & 0xffff0000u;
        a[j] += (f32x2){lo.f, hi.f};                 // v_pk_add_f32
        v[j] = vn[j];
      }
    }
    if (cmax > 0){
#pragma unroll
      for (int j=0;j<16;j++){
        union{u32 u; float f;} lo, hi;
        lo.u = v[j]<<16; hi.u = v[j] & 0xffff0000u;
        a[j] += (f32x2){lo.f, hi.f};
      }
    }
#pragma unroll
    for (int j=0;j<16;j++){
      int l = base_l + j, rl = l>>2, q = l&3;
      u32 pk = ((u32)f2bf(a[j].y)<<16) | (u32)f2bf(a[j].x);
      *reinterpret_cast<u32*>((char*)X_s + SWZ(rl, rl*1024 + q*256 + lane*4)) = pk;
    }
  }
  __syncthreads();

  // ---- GEMM1: pre[32x384] = [X_s | hbf] @ WfT^T ; wave tile 32(m) x 48(n) ----
  int n0 = wave*48;
  f32x4 acc[2][3] = {};
  const u16* Ah = hbf + (size_t)(m0+lr)*128 + lk*8;
  const u16* Bw = WfT + (size_t)(n0+lr)*640 + lk*8;
#pragma unroll
  for (int k=0;k<512;k+=32){
    bf16x8 b0 = *reinterpret_cast<const bf16x8*>(Bw + k);
    bf16x8 b1 = *reinterpret_cast<const bf16x8*>(Bw + 16*640 + k);
    bf16x8 b2 = *reinterpret_cast<const bf16x8*>(Bw + 32*640 + k);
#pragma unroll
    for (int mt=0;mt<2;mt++){
      int row = mt*16 + lr;
      bf16x8 aa = *reinterpret_cast<const bf16x8*>((const char*)X_s + SWZ(row, row*1024 + (k + lk*8)*2));
      acc[mt][0] = MFMA(aa, b0, acc[mt][0], 0,0,0);
      acc[mt][1] = MFMA(aa, b1, acc[mt][1], 0,0,0);
      acc[mt][2] = MFMA(aa, b2, acc[mt][2], 0,0,0);
    }
  }
#pragma unroll
  for (int k=0;k<128;k+=32){
    bf16x8 b0 = *reinterpret_cast<const bf16x8*>(Bw + 512 + k);
    bf16x8 b1 = *reinterpret_cast<const bf16x8*>(Bw + 16*640 + 512 + k);
    bf16x8 b2 = *reinterpret_cast<const bf16x8*>(Bw + 32*640 + 512 + k);
#pragma unroll
    for (int mt=0;mt<2;mt++){
      bf16x8 aa = *reinterpret_cast<const bf16x8*>(Ah + (size_t)mt*16*128 + k);
      acc[mt][0] = MFMA(aa, b0, acc[mt][0], 0,0,0);
      acc[mt][1] = MFMA(aa, b1, acc[mt][1], 0,0,0);
      acc[mt][2] = MFMA(aa, b2, acc[mt][2], 0,0,0);
    }
  }

  // ---- epilogue 1: r -> rh_s (swizzled), z -> z_s, hh -> hh_s ----
#pragma unroll
  for (int nt=0;nt<3;nt++){
    int oo = n0 + nt*16 + lr;
    float base = (oo<128) ? b_r[oo] : (oo<256) ? b_z[oo-128] : b_h[oo-256];
    float q0 = bv[oo], q1 = bv[384+oo], q2 = bv[768+oo], q3 = bv[1152+oo];
#pragma unroll
    for (int mt=0;mt<2;mt++){
#pragma unroll
      for (int i2=0;i2<4;i2++){
        int rl = mt*16 + lk*4 + i2;
        float v = acc[mt][nt][i2] + base
                + cnts[rl][0]*q0 + cnts[rl][1]*q1 + cnts[rl][2]*q2 + cnts[rl][3]*q3;
        if (oo < 128){
          float s = 1.f/(1.f + expf(-v));
          float hv = hf[(size_t)(m0+rl)*128 + oo];
          *reinterpret_cast<u16*>((char*)rh_s + SWZ(rl, rl*256 + oo*2)) = f2bf(s*hv);
        } else if (oo < 256){
          float s = 1.f/(1.f + expf(-v));
          z_s[rl*ZPAD + (oo-128)] = (u16)(s*65535.f + 0.5f);
        } else {
          hh_s[rl*ZPAD + (oo-256)] = f2bf(v);
        }
      }
    }
  }
  __syncthreads();

  // ---- GEMM2: H2[32x128] = rh_s @ WhbT^T ; wave tile 32(m) x 16(n) ----
  int c0 = wave*16;
  f32x4 acc2[2] = {};
  const u16* Bh = WhbT + (size_t)(c0+lr)*128 + lk*8;
#pragma unroll
  for (int k=0;k<128;k+=32){
    bf16x8 b = *reinterpret_cast<const bf16x8*>(Bh + k);
#pragma unroll
    for (int mt=0;mt<2;mt++){
      int rr = mt*16 + lr;
      bf16x8 aa = *reinterpret_cast<const bf16x8*>((char*)rh_s + SWZ(rr, rr*256 + (k + lk*8)*2));
      acc2[mt] = MFMA(aa, b, acc2[mt], 0,0,0);
    }
  }

  // ---- epilogue 2: h update ----
#pragma unroll
  for (int mt=0;mt<2;mt++){
#pragma unroll
    for (int i2=0;i2<4;i2++){
      int rl = mt*16 + lk*4 + i2, col = c0 + lr;
      size_t ix = (size_t)(m0+rl)*128 + col;
      float hhat = tanhf(acc2[mt][i2] + bf2f(hh_s[rl*ZPAD + col]));
      float zz = (float)z_s[rl*ZPAD + col] * (1.f/65535.f);
      float ho = hf[ix];
      float hn = ho + zz*(hhat - ho);
      hf[ix] = hn;
      hbf[ix] = f2bf(hn);
    }
  }
}

// ---------------- host ----------------

extern "C" void kernel_launch(void* const* d_in, const int* in_sizes, int n_in,
                              void* d_out, int out_size, void* d_ws, size_t ws_size,
                              hipStream_t stream)
{
  const float* prop  = (const float*)d_in[0];
  const float* A     = (const float*)d_in[1];
  const float* W_in  = (const float*)d_in[2];
  const float* b_in  = (const float*)d_in[3];
  const float* W_out = (const float*)d_in[4];
  const float* b_out = (const float*)d_in[5];
  const float* W_r   = (const float*)d_in[6];
  const float* b_r   = (const float*)d_in[7];
  const float* W_z   = (const float*)d_in[8];
  const float* b_z   = (const float*)d_in[9];
  const float* W_h   = (const float*)d_in[10];
  const float* b_h   = (const float*)d_in[11];

  char* ws = (char*)d_ws;
  size_t off = 0;
  auto nxt = [&](size_t bytes)->char*{ char* p = ws + off; off += (bytes + 255) & ~(size_t)255; return p; };
  int*   cnt4  = (int*)  nxt((size_t)ROWS*4*4);
  u16*   idx4  = (u16*)  nxt((size_t)ROWS*4*CAP*2);
  u16*   hbf   = (u16*)  nxt((size_t)(ROWS+1)*128*2);   // +1 sentinel zero row
  float* hf    = (float*)nxt((size_t)ROWS*128*4);
  u16*   WfT   = (u16*)  nxt((size_t)384*640*2);
  float* bv    = (float*)nxt((size_t)4*384*4);
  u16*   WhbT  = (u16*)  nxt((size_t)128*128*2);

  int fold_blocks = (640*384 + 4*384 + 128*128 + 255)/256;
  k_prep<<<4096 + fold_blocks, 256, 0, stream>>>(prop, hf, hbf,
      W_in, b_in, W_out, b_out, W_r, W_z, W_h, WfT, bv, WhbT);
  k_csr<<<ROWS, 256, 0, stream>>>(A, idx4, cnt4);

  for (int t=0; t<NSTEPS; t++){
    k_fused<<<ROWS/32, 512, 0, stream>>>(cnt4, idx4, WfT, bv, b_r, b_z, b_h, WhbT, hf, hbf);
  }

  hipMemcpyAsync(d_out, hf, (size_t)ROWS*128*4, hipMemcpyDeviceToDevice, stream);
}